// Round 3
// baseline (426.231 us; speedup 1.0000x reference)
//
#include <hip/hip_runtime.h>
#include <hip/hip_bf16.h>
#include <math.h>

// Problem constants (from reference setup_inputs)
#define BATCH 8
#define SEQ   1536
#define DIM   1024
#define SEQ2  (2*SEQ)          // 3072
#define TEMP_INV 20.0f         // 1 / 0.05

// GEMM tiling
#define BM 128
#define BN 128
#define BK 64
#define KITERS (DIM/BK)                // 16
#define TILES  (SEQ2 / BM)             // 24
#define NPAIRS (TILES * (TILES+1) / 2) // 300 upper-triangular tile pairs
#define TOTAL  (NPAIRS * BATCH)        // 2400
#define GRID   800
#define PASSES (TOTAL / GRID)          // 3 pairs per block (persistent)

typedef __bf16 bf16x8 __attribute__((ext_vector_type(8)));
typedef float  f32x4  __attribute__((ext_vector_type(4)));

#define GLOBAL_AS __attribute__((address_space(1)))
#define LDS_AS    __attribute__((address_space(3)))

__device__ inline void async_ld16(const void* g, void* lds_uniform) {
    // gfx950: direct global->LDS, 16B/lane; LDS dest = wave-uniform base + lane*16
    __builtin_amdgcn_global_load_lds((const GLOBAL_AS void*)g, (LDS_AS void*)lds_uniform, 16, 0, 0);
}

__device__ inline float wave_red64(float v) {
    #pragma unroll
    for (int m = 32; m > 0; m >>= 1) v += __shfl_xor(v, m, 64);
    return v;
}

__device__ inline void decode_pair(int lin, int& b, int& ibase, int& jbase, bool& diag) {
    b = lin / NPAIRS;
    int p = lin - b * NPAIRS;
    int ti = 0;
    while (p >= TILES - ti) { p -= TILES - ti; ti++; }
    int tj = ti + p;
    ibase = ti * BM; jbase = tj * BN; diag = (ti == tj);
}

// ---------------------------------------------------------------------------
// Kernel 1: L2-normalize both views -> bf16 feats [B][2S][D]; fp32 pos cosine;
// zero-init Ng.  One WAVE per token: no barriers, 8 16B loads in flight.
// ---------------------------------------------------------------------------
__global__ __launch_bounds__(256) void normalize_kernel(
        const float* __restrict__ h1, const float* __restrict__ h2,
        __hip_bfloat16* __restrict__ feats, float* __restrict__ pos_cos,
        float* __restrict__ Ng) {
    int w = threadIdx.x >> 6, lane = threadIdx.x & 63;
    int tok = blockIdx.x * 4 + w;                 // 0 .. B*S-1
    int b = tok / SEQ, s = tok - b * SEQ;

    const float4* a4 = (const float4*)(h1 + (size_t)tok * DIM);
    const float4* b4 = (const float4*)(h2 + (size_t)tok * DIM);
    float4 av[4], bv[4];
    #pragma unroll
    for (int it = 0; it < 4; it++) { av[it] = a4[lane + 64*it]; bv[it] = b4[lane + 64*it]; }

    float ss1 = 0.f, ss2 = 0.f, sd = 0.f;
    #pragma unroll
    for (int it = 0; it < 4; it++) {
        ss1 += av[it].x*av[it].x + av[it].y*av[it].y + av[it].z*av[it].z + av[it].w*av[it].w;
        ss2 += bv[it].x*bv[it].x + bv[it].y*bv[it].y + bv[it].z*bv[it].z + bv[it].w*bv[it].w;
        sd  += av[it].x*bv[it].x + av[it].y*bv[it].y + av[it].z*bv[it].z + av[it].w*bv[it].w;
    }
    ss1 = wave_red64(ss1); ss2 = wave_red64(ss2); sd = wave_red64(sd);

    float sc1 = 1.0f / fmaxf(sqrtf(ss1), 1e-12f);
    float sc2 = 1.0f / fmaxf(sqrtf(ss2), 1e-12f);

    __hip_bfloat16* f1row = feats + ((size_t)b * SEQ2 + s) * DIM;
    __hip_bfloat16* f2row = feats + ((size_t)b * SEQ2 + SEQ + s) * DIM;
    #pragma unroll
    for (int it = 0; it < 4; it++) {
        ushort4 o1, o2;
        o1.x = __bfloat16_as_ushort(__float2bfloat16(av[it].x * sc1));
        o1.y = __bfloat16_as_ushort(__float2bfloat16(av[it].y * sc1));
        o1.z = __bfloat16_as_ushort(__float2bfloat16(av[it].z * sc1));
        o1.w = __bfloat16_as_ushort(__float2bfloat16(av[it].w * sc1));
        o2.x = __bfloat16_as_ushort(__float2bfloat16(bv[it].x * sc2));
        o2.y = __bfloat16_as_ushort(__float2bfloat16(bv[it].y * sc2));
        o2.z = __bfloat16_as_ushort(__float2bfloat16(bv[it].z * sc2));
        o2.w = __bfloat16_as_ushort(__float2bfloat16(bv[it].w * sc2));
        ((ushort4*)f1row)[lane + 64*it] = o1;
        ((ushort4*)f2row)[lane + 64*it] = o2;
    }
    if (lane == 0) {
        pos_cos[tok] = sd * sc1 * sc2;
        Ng[2*tok] = 0.0f;
        Ng[2*tok + 1] = 0.0f;
    }
}

// ---------------------------------------------------------------------------
// Kernel 2: symmetric fused sim-GEMM + exp + neg-mask, persistent blocks.
// Upper-triangular tile pairs only; off-diag tiles accumulate row sums
// (-> Ng[i]) and col sums (-> Ng[j]).  BK=64, one barrier pair per k-iter
// with DMA issued BEFORE the MFMAs (overlap), and next pair's first DMA
// issued before the epilogue (overlap).
// LDS chunk swizzle: 16B chunk c of row r stored at slot c ^ (r&7), realized
// by permuting each staging lane's GLOBAL source chunk (DMA lane->LDS fixed).
// ---------------------------------------------------------------------------
__global__ __launch_bounds__(256) void gemm_ng_kernel(
        const __hip_bfloat16* __restrict__ feats, const int* __restrict__ mask,
        float* __restrict__ Ng) {
    __shared__ __align__(16) __hip_bfloat16 As[BM][BK];  // 16 KB
    __shared__ __align__(16) __hip_bfloat16 Bs[BN][BK];  // 16 KB
    __shared__ float mrow_s[BM];
    __shared__ float mcol_s[BN];

    int t = threadIdx.x;
    int lane = t & 63, w = t >> 6;
    int wrow = w >> 1, wcol = w & 1;       // 2x2 waves -> 64x64 each
    int colq = lane & 15, quad = lane >> 4;

    int lin = blockIdx.x;
    int b, ibase, jbase; bool diag;
    decode_pair(lin, b, ibase, jbase, diag);

    // staging source: thread t covers row r = t>>3 (of 32 per issue), stored
    // slot t&7; logical source chunk = (t&7) ^ (r&7).
    int sr = t >> 3;
    int sc = (t & 7) ^ (sr & 7);
    const __hip_bfloat16* fb = feats + (size_t)b * SEQ2 * DIM;
    const char* a0 = (const char*)(fb + (size_t)(ibase + sr) * DIM) + sc * 16;
    const char* b0 = (const char*)(fb + (size_t)(jbase + sr) * DIM) + sc * 16;

    auto stage = [&](size_t kb) {
        #pragma unroll
        for (int q = 0; q < 4; q++) {   // q*32 rows; 32*DIM*2 = 65536 B
            async_ld16(a0 + (size_t)q * 65536 + kb, (char*)&As[0][0] + q * 4096 + w * 1024);
            async_ld16(b0 + (size_t)q * 65536 + kb, (char*)&Bs[0][0] + q * 4096 + w * 1024);
        }
    };
    auto write_masks = [&]() {
        if (t < BM) {
            int i = ibase + t; int im = (i < SEQ) ? i : i - SEQ;
            mrow_s[t] = mask[b * SEQ + im] ? 1.0f : 0.0f;
        } else {
            int j = jbase + (t - BM); int jm = (j < SEQ) ? j : j - SEQ;
            mcol_s[t - BM] = mask[b * SEQ + jm] ? 1.0f : 0.0f;
        }
    };

    write_masks();
    stage(0);
    asm volatile("s_waitcnt vmcnt(0)" ::: "memory");
    __syncthreads();

    int s0 = (quad ^ (colq & 7)) * 8;      // element offset of ksub0 chunk
    for (int pass = 0; pass < PASSES; pass++) {
        f32x4 acc[4][4] = {};
        bf16x8 af0[4], af1[4], bg0[4], bg1[4];

        auto read_frags = [&]() {
            #pragma unroll
            for (int mi = 0; mi < 4; mi++) {
                int row = wrow * 64 + mi * 16 + colq;   // row&7 == colq&7
                af0[mi] = *(const bf16x8*)&As[row][s0];
                af1[mi] = *(const bf16x8*)&As[row][s0 ^ 32];
            }
            #pragma unroll
            for (int nj = 0; nj < 4; nj++) {
                int row = wcol * 64 + nj * 16 + colq;
                bg0[nj] = *(const bf16x8*)&Bs[row][s0];
                bg1[nj] = *(const bf16x8*)&Bs[row][s0 ^ 32];
            }
        };
        auto do_mfma = [&]() {
            #pragma unroll
            for (int mi = 0; mi < 4; mi++)
                #pragma unroll
                for (int nj = 0; nj < 4; nj++)
                    acc[mi][nj] = __builtin_amdgcn_mfma_f32_16x16x32_bf16(
                        af0[mi], bg0[nj], acc[mi][nj], 0, 0, 0);
            #pragma unroll
            for (int mi = 0; mi < 4; mi++)
                #pragma unroll
                for (int nj = 0; nj < 4; nj++)
                    acc[mi][nj] = __builtin_amdgcn_mfma_f32_16x16x32_bf16(
                        af1[mi], bg1[nj], acc[mi][nj], 0, 0, 0);
        };

        #pragma unroll 1
        for (int it = 0; it < KITERS - 1; it++) {
            read_frags();
            __syncthreads();                 // all waves done with this LDS tile
            stage((size_t)(it + 1) * BK * 2);// DMA flight overlaps the MFMAs
            do_mfma();
            asm volatile("s_waitcnt vmcnt(0)" ::: "memory");
            __syncthreads();
        }
        // last k-tile: overlap NEXT pair's first DMA with MFMAs + epilogue
        read_frags();
        __syncthreads();
        int cur_b = b, cur_i = ibase, cur_j = jbase; bool cur_diag = diag;
        if (pass < PASSES - 1) {
            lin += GRID;
            decode_pair(lin, b, ibase, jbase, diag);
            fb = feats + (size_t)b * SEQ2 * DIM;
            a0 = (const char*)(fb + (size_t)(ibase + sr) * DIM) + sc * 16;
            b0 = (const char*)(fb + (size_t)(jbase + sr) * DIM) + sc * 16;
            stage(0);
        }
        do_mfma();

        // Epilogue.  C/D layout: col = colq, row = quad*4 + reg.
        float mj[4]; int jglob[4];
        #pragma unroll
        for (int nj = 0; nj < 4; nj++) {
            int jl = wcol * 64 + nj * 16 + colq;
            mj[nj] = mcol_s[jl];
            jglob[nj] = cur_j + jl;
        }
        float colsum[4] = {0.f, 0.f, 0.f, 0.f};
        #pragma unroll
        for (int mi = 0; mi < 4; mi++) {
            int il0 = wrow * 64 + mi * 16 + quad * 4;
            float rsum[4] = {0.f, 0.f, 0.f, 0.f};
            float mr[4];
            #pragma unroll
            for (int r = 0; r < 4; r++) mr[r] = mrow_s[il0 + r];
            #pragma unroll
            for (int nj = 0; nj < 4; nj++) {
                #pragma unroll
                for (int r = 0; r < 4; r++) {
                    int d = (cur_i + il0 + r) - jglob[nj];
                    bool same = (d == 0) | (d == SEQ) | (d == -SEQ);
                    float e = same ? 0.0f : __expf(acc[mi][nj][r] * TEMP_INV);
                    rsum[r] += e * mj[nj];
                    colsum[nj] += e * mr[r];
                }
            }
            #pragma unroll
            for (int r = 0; r < 4; r++) {
                float v = rsum[r];
                #pragma unroll
                for (int m = 1; m < 16; m <<= 1) v += __shfl_xor(v, m, 64);
                if (colq == 0)
                    atomicAdd(&Ng[cur_b * SEQ2 + cur_i + il0 + r], v);
            }
        }
        if (!cur_diag) {
            #pragma unroll
            for (int nj = 0; nj < 4; nj++) {
                float v = colsum[nj];
                v += __shfl_xor(v, 16, 64);
                v += __shfl_xor(v, 32, 64);
                if (quad == 0)
                    atomicAdd(&Ng[cur_b * SEQ2 + jglob[nj]], v);
            }
        }
        __syncthreads();                     // all waves done reading cur masks
        if (pass < PASSES - 1) write_masks();
        asm volatile("s_waitcnt vmcnt(0)" ::: "memory");
        __syncthreads();
    }
}

// ---------------------------------------------------------------------------
// Kernel 3: per-batch masked mean of per-token loss.
// per_tok[i] = log1p(Ng[i] * exp(-pos_sim/T))
// ---------------------------------------------------------------------------
__global__ __launch_bounds__(256) void loss_kernel(
        const float* __restrict__ Ng, const float* __restrict__ pos_cos,
        const int* __restrict__ mask, float* __restrict__ per_sample) {
    int b = blockIdx.x, t = threadIdx.x;
    float sum = 0.f, cnt = 0.f;
    for (int i = t; i < SEQ2; i += 256) {
        int im = (i < SEQ) ? i : i - SEQ;
        if (mask[b * SEQ + im]) {
            float ps = pos_cos[b * SEQ + im] * TEMP_INV;
            float ng = Ng[b * SEQ2 + i];
            sum += log1pf(ng * __expf(-ps));
            cnt += 1.0f;
        }
    }
    sum = wave_red64(sum); cnt = wave_red64(cnt);
    __shared__ float rs[4], rc[4];
    int lane = t & 63, w = t >> 6;
    if (lane == 0) { rs[w] = sum; rc[w] = cnt; }
    __syncthreads();
    if (t == 0) {
        float s = rs[0]+rs[1]+rs[2]+rs[3];
        float c = rc[0]+rc[1]+rc[2]+rc[3];
        per_sample[b] = s / c;
    }
}

__global__ void final_kernel(const float* __restrict__ per_sample, float* __restrict__ out) {
    if (threadIdx.x == 0) {
        float s = 0.f;
        #pragma unroll
        for (int b = 0; b < BATCH; b++) s += per_sample[b];
        out[0] = s / (float)BATCH;
    }
}

// ---------------------------------------------------------------------------
extern "C" void kernel_launch(void* const* d_in, const int* in_sizes, int n_in,
                              void* d_out, int out_size, void* d_ws, size_t ws_size,
                              hipStream_t stream) {
    const float* h1  = (const float*)d_in[0];
    const float* h2  = (const float*)d_in[1];
    const int* mask  = (const int*)d_in[2];
    float* out       = (float*)d_out;

    char* ws = (char*)d_ws;
    size_t feats_bytes = (size_t)BATCH * SEQ2 * DIM * 2;      // 50,331,648
    __hip_bfloat16* feats = (__hip_bfloat16*)ws;
    float* pos_cos    = (float*)(ws + feats_bytes);
    float* Ng         = (float*)(ws + feats_bytes + (size_t)BATCH * SEQ * 4);
    float* per_sample = (float*)(ws + feats_bytes + (size_t)BATCH * SEQ * 4
                                 + (size_t)BATCH * SEQ2 * 4);

    normalize_kernel<<<BATCH * SEQ / 4, 256, 0, stream>>>(h1, h2, feats, pos_cos, Ng);

    gemm_ng_kernel<<<GRID, 256, 0, stream>>>(feats, mask, Ng);

    loss_kernel<<<BATCH, 256, 0, stream>>>(Ng, pos_cos, mask, per_sample);
    final_kernel<<<1, 64, 0, stream>>>(per_sample, out);
}

// Round 4
// 274.710 us; speedup vs baseline: 1.5516x; 1.5516x over previous
//
#include <hip/hip_runtime.h>
#include <hip/hip_bf16.h>
#include <math.h>

// Problem constants (from reference setup_inputs)
#define BATCH 8
#define SEQ   1536
#define DIM   1024
#define SEQ2  (2*SEQ)          // 3072
#define TEMP_INV 20.0f         // 1 / 0.05

// GEMM tiling
#define BM 128
#define BN 128
#define BK 64
#define KITERS (DIM/BK)                // 16
#define TILES  (SEQ2 / BM)             // 24
#define NPAIRS (TILES * (TILES+1) / 2) // 300 upper-triangular tile pairs

typedef __bf16 bf16x8 __attribute__((ext_vector_type(8)));
typedef float  f32x4  __attribute__((ext_vector_type(4)));

#define GLOBAL_AS __attribute__((address_space(1)))
#define LDS_AS    __attribute__((address_space(3)))

__device__ inline void async_ld16(const void* g, void* lds_uniform) {
    // gfx950: direct global->LDS, 16B/lane; LDS dest = wave-uniform base + lane*16
    __builtin_amdgcn_global_load_lds((const GLOBAL_AS void*)g, (LDS_AS void*)lds_uniform, 16, 0, 0);
}

__device__ inline float wave_red64(float v) {
    #pragma unroll
    for (int m = 32; m > 0; m >>= 1) v += __shfl_xor(v, m, 64);
    return v;
}

// ---------------------------------------------------------------------------
// Kernel 1: L2-normalize both views -> bf16 feats [B][2S][D]; fp32 pos cosine;
// zero-init Ng.  One WAVE per token: no barriers.
// ---------------------------------------------------------------------------
__global__ __launch_bounds__(256) void normalize_kernel(
        const float* __restrict__ h1, const float* __restrict__ h2,
        __hip_bfloat16* __restrict__ feats, float* __restrict__ pos_cos,
        float* __restrict__ Ng) {
    int w = threadIdx.x >> 6, lane = threadIdx.x & 63;
    int tok = blockIdx.x * 4 + w;                 // 0 .. B*S-1
    int b = tok / SEQ, s = tok - b * SEQ;

    const float4* a4 = (const float4*)(h1 + (size_t)tok * DIM);
    const float4* b4 = (const float4*)(h2 + (size_t)tok * DIM);
    float4 av[4], bv[4];
    #pragma unroll
    for (int it = 0; it < 4; it++) { av[it] = a4[lane + 64*it]; bv[it] = b4[lane + 64*it]; }

    float ss1 = 0.f, ss2 = 0.f, sd = 0.f;
    #pragma unroll
    for (int it = 0; it < 4; it++) {
        ss1 += av[it].x*av[it].x + av[it].y*av[it].y + av[it].z*av[it].z + av[it].w*av[it].w;
        ss2 += bv[it].x*bv[it].x + bv[it].y*bv[it].y + bv[it].z*bv[it].z + bv[it].w*bv[it].w;
        sd  += av[it].x*bv[it].x + av[it].y*bv[it].y + av[it].z*bv[it].z + av[it].w*bv[it].w;
    }
    ss1 = wave_red64(ss1); ss2 = wave_red64(ss2); sd = wave_red64(sd);

    float sc1 = 1.0f / fmaxf(sqrtf(ss1), 1e-12f);
    float sc2 = 1.0f / fmaxf(sqrtf(ss2), 1e-12f);

    __hip_bfloat16* f1row = feats + ((size_t)b * SEQ2 + s) * DIM;
    __hip_bfloat16* f2row = feats + ((size_t)b * SEQ2 + SEQ + s) * DIM;
    #pragma unroll
    for (int it = 0; it < 4; it++) {
        ushort4 o1, o2;
        o1.x = __bfloat16_as_ushort(__float2bfloat16(av[it].x * sc1));
        o1.y = __bfloat16_as_ushort(__float2bfloat16(av[it].y * sc1));
        o1.z = __bfloat16_as_ushort(__float2bfloat16(av[it].z * sc1));
        o1.w = __bfloat16_as_ushort(__float2bfloat16(av[it].w * sc1));
        o2.x = __bfloat16_as_ushort(__float2bfloat16(bv[it].x * sc2));
        o2.y = __bfloat16_as_ushort(__float2bfloat16(bv[it].y * sc2));
        o2.z = __bfloat16_as_ushort(__float2bfloat16(bv[it].z * sc2));
        o2.w = __bfloat16_as_ushort(__float2bfloat16(bv[it].w * sc2));
        ((ushort4*)f1row)[lane + 64*it] = o1;
        ((ushort4*)f2row)[lane + 64*it] = o2;
    }
    if (lane == 0) {
        pos_cos[tok] = sd * sc1 * sc2;
        Ng[2*tok] = 0.0f;
        Ng[2*tok + 1] = 0.0f;
    }
}

// ---------------------------------------------------------------------------
// Kernel 2: symmetric fused sim-GEMM + exp + neg-mask.
// R2 skeleton (non-persistent, 2400 blocks, simple m97 K-loop) with BK=64 and
// the R3 HW-verified zero-conflict LDS layout:
//   16B chunk c of row r stored at slot c ^ (r&7)  (128-B rows span all banks)
// realized by permuting each staging lane's GLOBAL source chunk.
// ---------------------------------------------------------------------------
__global__ __launch_bounds__(256) void gemm_ng_kernel(
        const __hip_bfloat16* __restrict__ feats, const int* __restrict__ mask,
        float* __restrict__ Ng) {
    int b = blockIdx.z;
    // decode triangular pair index -> (ti, tj), ti <= tj
    int p = blockIdx.x;
    int ti = 0;
    while (p >= TILES - ti) { p -= TILES - ti; ti++; }
    int tj = ti + p;
    int ibase = ti * BM, jbase = tj * BN;
    bool isdiag = (ti == tj);

    const __hip_bfloat16* fb = feats + (size_t)b * SEQ2 * DIM;

    __shared__ __align__(16) __hip_bfloat16 As[BM][BK];  // 16 KB (swizzled chunks)
    __shared__ __align__(16) __hip_bfloat16 Bs[BN][BK];  // 16 KB
    __shared__ float mrow_s[BM];
    __shared__ float mcol_s[BN];

    int t = threadIdx.x;
    int lane = t & 63, w = t >> 6;
    int wrow = w >> 1, wcol = w & 1;       // 2x2 waves -> 64x64 each
    int colq = lane & 15, quad = lane >> 4;

    // stage masks (as float) for the tile's rows/cols
    if (t < BM) {
        int i = ibase + t; int im = (i < SEQ) ? i : i - SEQ;
        mrow_s[t] = mask[b * SEQ + im] ? 1.0f : 0.0f;
    } else {
        int j = jbase + (t - BM); int jm = (j < SEQ) ? j : j - SEQ;
        mcol_s[t - BM] = mask[b * SEQ + jm] ? 1.0f : 0.0f;
    }

    // Staging: per issue, thread t covers row sr = t>>3 (32 rows), stored slot
    // t&7; logical source chunk = (t&7) ^ (sr&7).  (sr+32k)&7 == sr&7.
    int sr = t >> 3;
    int sc = (t & 7) ^ (sr & 7);
    const char* a0 = (const char*)(fb + (size_t)(ibase + sr) * DIM) + sc * 16;
    const char* b0 = (const char*)(fb + (size_t)(jbase + sr) * DIM) + sc * 16;

    f32x4 acc[4][4] = {};
    int s0 = (quad ^ (colq & 7)) * 8;      // element offset of ksub0 chunk

    for (int k0 = 0; k0 < DIM; k0 += BK) {
        __syncthreads();                    // LDS reuse from previous iter
        size_t kb = (size_t)k0 * 2;         // byte offset along k
        #pragma unroll
        for (int q = 0; q < 4; q++) {       // q*32 rows; 32*DIM*2 = 65536 B
            async_ld16(a0 + (size_t)q * 65536 + kb, (char*)&As[0][0] + q * 4096 + w * 1024);
            async_ld16(b0 + (size_t)q * 65536 + kb, (char*)&Bs[0][0] + q * 4096 + w * 1024);
        }
        asm volatile("s_waitcnt vmcnt(0)" ::: "memory");
        __syncthreads();

        bf16x8 af0[4], af1[4], bg0[4], bg1[4];
        #pragma unroll
        for (int mi = 0; mi < 4; mi++) {
            int row = wrow * 64 + mi * 16 + colq;   // row&7 == colq&7
            af0[mi] = *(const bf16x8*)&As[row][s0];
            af1[mi] = *(const bf16x8*)&As[row][s0 ^ 32];
        }
        #pragma unroll
        for (int nj = 0; nj < 4; nj++) {
            int row = wcol * 64 + nj * 16 + colq;
            bg0[nj] = *(const bf16x8*)&Bs[row][s0];
            bg1[nj] = *(const bf16x8*)&Bs[row][s0 ^ 32];
        }

        #pragma unroll
        for (int mi = 0; mi < 4; mi++)
            #pragma unroll
            for (int nj = 0; nj < 4; nj++)
                acc[mi][nj] = __builtin_amdgcn_mfma_f32_16x16x32_bf16(
                    af0[mi], bg0[nj], acc[mi][nj], 0, 0, 0);
        #pragma unroll
        for (int mi = 0; mi < 4; mi++)
            #pragma unroll
            for (int nj = 0; nj < 4; nj++)
                acc[mi][nj] = __builtin_amdgcn_mfma_f32_16x16x32_bf16(
                    af1[mi], bg1[nj], acc[mi][nj], 0, 0, 0);
    }

    // Epilogue.  C/D layout: col = colq, row = quad*4 + reg.
    float mj[4]; int jglob[4];
    #pragma unroll
    for (int nj = 0; nj < 4; nj++) {
        int jl = wcol * 64 + nj * 16 + colq;
        mj[nj] = mcol_s[jl];
        jglob[nj] = jbase + jl;
    }
    float colsum[4] = {0.f, 0.f, 0.f, 0.f};

    #pragma unroll
    for (int mi = 0; mi < 4; mi++) {
        int il0 = wrow * 64 + mi * 16 + quad * 4;
        float rsum[4] = {0.f, 0.f, 0.f, 0.f};
        float mr[4];
        #pragma unroll
        for (int r = 0; r < 4; r++) mr[r] = mrow_s[il0 + r];
        #pragma unroll
        for (int nj = 0; nj < 4; nj++) {
            #pragma unroll
            for (int r = 0; r < 4; r++) {
                int d = (ibase + il0 + r) - jglob[nj];
                bool same = (d == 0) | (d == SEQ) | (d == -SEQ);
                float e = same ? 0.0f : __expf(acc[mi][nj][r] * TEMP_INV);
                rsum[r] += e * mj[nj];
                colsum[nj] += e * mr[r];
            }
        }
        // reduce each row sum across the 16 column lanes
        #pragma unroll
        for (int r = 0; r < 4; r++) {
            float v = rsum[r];
            #pragma unroll
            for (int m = 1; m < 16; m <<= 1) v += __shfl_xor(v, m, 64);
            if (colq == 0)
                atomicAdd(&Ng[b * SEQ2 + ibase + il0 + r], v);
        }
    }

    if (!isdiag) {
        // reduce col sums across the 4 quads
        #pragma unroll
        for (int nj = 0; nj < 4; nj++) {
            float v = colsum[nj];
            v += __shfl_xor(v, 16, 64);
            v += __shfl_xor(v, 32, 64);
            if (quad == 0)
                atomicAdd(&Ng[b * SEQ2 + jglob[nj]], v);
        }
    }
}

// ---------------------------------------------------------------------------
// Kernel 3: per-batch masked mean of per-token loss.
// per_tok[i] = log1p(Ng[i] * exp(-pos_sim/T))
// ---------------------------------------------------------------------------
__global__ __launch_bounds__(256) void loss_kernel(
        const float* __restrict__ Ng, const float* __restrict__ pos_cos,
        const int* __restrict__ mask, float* __restrict__ per_sample) {
    int b = blockIdx.x, t = threadIdx.x;
    float sum = 0.f, cnt = 0.f;
    for (int i = t; i < SEQ2; i += 256) {
        int im = (i < SEQ) ? i : i - SEQ;
        if (mask[b * SEQ + im]) {
            float ps = pos_cos[b * SEQ + im] * TEMP_INV;
            float ng = Ng[b * SEQ2 + i];
            sum += log1pf(ng * __expf(-ps));
            cnt += 1.0f;
        }
    }
    sum = wave_red64(sum); cnt = wave_red64(cnt);
    __shared__ float rs[4], rc[4];
    int lane = t & 63, w = t >> 6;
    if (lane == 0) { rs[w] = sum; rc[w] = cnt; }
    __syncthreads();
    if (t == 0) {
        float s = rs[0]+rs[1]+rs[2]+rs[3];
        float c = rc[0]+rc[1]+rc[2]+rc[3];
        per_sample[b] = s / c;
    }
}

__global__ void final_kernel(const float* __restrict__ per_sample, float* __restrict__ out) {
    if (threadIdx.x == 0) {
        float s = 0.f;
        #pragma unroll
        for (int b = 0; b < BATCH; b++) s += per_sample[b];
        out[0] = s / (float)BATCH;
    }
}

// ---------------------------------------------------------------------------
extern "C" void kernel_launch(void* const* d_in, const int* in_sizes, int n_in,
                              void* d_out, int out_size, void* d_ws, size_t ws_size,
                              hipStream_t stream) {
    const float* h1  = (const float*)d_in[0];
    const float* h2  = (const float*)d_in[1];
    const int* mask  = (const int*)d_in[2];
    float* out       = (float*)d_out;

    char* ws = (char*)d_ws;
    size_t feats_bytes = (size_t)BATCH * SEQ2 * DIM * 2;      // 50,331,648
    __hip_bfloat16* feats = (__hip_bfloat16*)ws;
    float* pos_cos    = (float*)(ws + feats_bytes);
    float* Ng         = (float*)(ws + feats_bytes + (size_t)BATCH * SEQ * 4);
    float* per_sample = (float*)(ws + feats_bytes + (size_t)BATCH * SEQ * 4
                                 + (size_t)BATCH * SEQ2 * 4);

    normalize_kernel<<<BATCH * SEQ / 4, 256, 0, stream>>>(h1, h2, feats, pos_cos, Ng);

    dim3 g2(NPAIRS, 1, BATCH);
    gemm_ng_kernel<<<g2, 256, 0, stream>>>(feats, mask, Ng);

    loss_kernel<<<BATCH, 256, 0, stream>>>(Ng, pos_cos, mask, per_sample);
    final_kernel<<<1, 64, 0, stream>>>(per_sample, out);
}

// Round 5
// 271.719 us; speedup vs baseline: 1.5686x; 1.0110x over previous
//
#include <hip/hip_runtime.h>
#include <hip/hip_bf16.h>
#include <math.h>

// Problem constants (from reference setup_inputs)
#define BATCH 8
#define SEQ   1536
#define DIM   1024
#define SEQ2  (2*SEQ)          // 3072
#define TEMP_INV 20.0f         // 1 / 0.05

// GEMM tiling
#define BM 128
#define BN 128
#define BK 32
#define KITERS (DIM/BK)                // 32
#define TILES  (SEQ2 / BM)             // 24
#define NPAIRS (TILES * (TILES+1) / 2) // 300 upper-triangular tile pairs

typedef __bf16 bf16x8 __attribute__((ext_vector_type(8)));
typedef float  f32x4  __attribute__((ext_vector_type(4)));

#define GLOBAL_AS __attribute__((address_space(1)))
#define LDS_AS    __attribute__((address_space(3)))

__device__ inline void async_ld16(const void* g, void* lds_uniform) {
    // gfx950: direct global->LDS, 16B/lane; LDS dest = wave-uniform base + lane*16
    __builtin_amdgcn_global_load_lds((const GLOBAL_AS void*)g, (LDS_AS void*)lds_uniform, 16, 0, 0);
}

__device__ inline float wave_red64(float v) {
    #pragma unroll
    for (int m = 32; m > 0; m >>= 1) v += __shfl_xor(v, m, 64);
    return v;
}

// chunk swizzle within 64-B rows (same as R2; conflicts are inherent either way)
__device__ inline int swz(int r) { return (r + (r >> 2)) & 3; }

// ---------------------------------------------------------------------------
// Kernel 1: L2-normalize both views -> bf16 feats [B][2S][D]; fp32 pos cosine;
// zero-init Ng.  One WAVE per token: no barriers.
// ---------------------------------------------------------------------------
__global__ __launch_bounds__(256) void normalize_kernel(
        const float* __restrict__ h1, const float* __restrict__ h2,
        __hip_bfloat16* __restrict__ feats, float* __restrict__ pos_cos,
        float* __restrict__ Ng) {
    int w = threadIdx.x >> 6, lane = threadIdx.x & 63;
    int tok = blockIdx.x * 4 + w;                 // 0 .. B*S-1
    int b = tok / SEQ, s = tok - b * SEQ;

    const float4* a4 = (const float4*)(h1 + (size_t)tok * DIM);
    const float4* b4 = (const float4*)(h2 + (size_t)tok * DIM);
    float4 av[4], bv[4];
    #pragma unroll
    for (int it = 0; it < 4; it++) { av[it] = a4[lane + 64*it]; bv[it] = b4[lane + 64*it]; }

    float ss1 = 0.f, ss2 = 0.f, sd = 0.f;
    #pragma unroll
    for (int it = 0; it < 4; it++) {
        ss1 += av[it].x*av[it].x + av[it].y*av[it].y + av[it].z*av[it].z + av[it].w*av[it].w;
        ss2 += bv[it].x*bv[it].x + bv[it].y*bv[it].y + bv[it].z*bv[it].z + bv[it].w*bv[it].w;
        sd  += av[it].x*bv[it].x + av[it].y*bv[it].y + av[it].z*bv[it].z + av[it].w*bv[it].w;
    }
    ss1 = wave_red64(ss1); ss2 = wave_red64(ss2); sd = wave_red64(sd);

    float sc1 = 1.0f / fmaxf(sqrtf(ss1), 1e-12f);
    float sc2 = 1.0f / fmaxf(sqrtf(ss2), 1e-12f);

    __hip_bfloat16* f1row = feats + ((size_t)b * SEQ2 + s) * DIM;
    __hip_bfloat16* f2row = feats + ((size_t)b * SEQ2 + SEQ + s) * DIM;
    #pragma unroll
    for (int it = 0; it < 4; it++) {
        ushort4 o1, o2;
        o1.x = __bfloat16_as_ushort(__float2bfloat16(av[it].x * sc1));
        o1.y = __bfloat16_as_ushort(__float2bfloat16(av[it].y * sc1));
        o1.z = __bfloat16_as_ushort(__float2bfloat16(av[it].z * sc1));
        o1.w = __bfloat16_as_ushort(__float2bfloat16(av[it].w * sc1));
        o2.x = __bfloat16_as_ushort(__float2bfloat16(bv[it].x * sc2));
        o2.y = __bfloat16_as_ushort(__float2bfloat16(bv[it].y * sc2));
        o2.z = __bfloat16_as_ushort(__float2bfloat16(bv[it].z * sc2));
        o2.w = __bfloat16_as_ushort(__float2bfloat16(bv[it].w * sc2));
        ((ushort4*)f1row)[lane + 64*it] = o1;
        ((ushort4*)f2row)[lane + 64*it] = o2;
    }
    if (lane == 0) {
        pos_cos[tok] = sd * sc1 * sc2;
        Ng[2*tok] = 0.0f;
        Ng[2*tok + 1] = 0.0f;
    }
}

// ---------------------------------------------------------------------------
// Kernel 2: symmetric fused sim-GEMM + exp + neg-mask.
// R2 skeleton (non-persistent, 2400 blocks, BK=32) + single-barrier
// DOUBLE-BUFFERED K-loop:
//   sync -> stage(k+1, buf^1) -> read frags(buf) -> MFMA -> buf^=1
// With prefetch distance 1 the compiler's mandatory vmcnt(0)-before-barrier
// drains exactly the DMAs we need (issued one full iter earlier), so each
// DMA flight overlaps the whole ds_read+MFMA stretch. One barrier per iter.
// ---------------------------------------------------------------------------
__global__ __launch_bounds__(256) void gemm_ng_kernel(
        const __hip_bfloat16* __restrict__ feats, const int* __restrict__ mask,
        float* __restrict__ Ng) {
    int b = blockIdx.z;
    // decode triangular pair index -> (ti, tj), ti <= tj
    int p = blockIdx.x;
    int ti = 0;
    while (p >= TILES - ti) { p -= TILES - ti; ti++; }
    int tj = ti + p;
    int ibase = ti * BM, jbase = tj * BN;
    bool isdiag = (ti == tj);

    const __hip_bfloat16* fb = feats + (size_t)b * SEQ2 * DIM;

    __shared__ __align__(16) __hip_bfloat16 As[2][BM][BK];  // 2 x 8 KB
    __shared__ __align__(16) __hip_bfloat16 Bs[2][BM][BK];  // 2 x 8 KB
    __shared__ float mrow_s[BM];
    __shared__ float mcol_s[BN];

    int t = threadIdx.x;
    int lane = t & 63, w = t >> 6;
    int wrow = w >> 1, wcol = w & 1;       // 2x2 waves -> 64x64 each
    int colq = lane & 15, quad = lane >> 4;

    // stage masks (as float) for the tile's rows/cols
    if (t < BM) {
        int i = ibase + t; int im = (i < SEQ) ? i : i - SEQ;
        mrow_s[t] = mask[b * SEQ + im] ? 1.0f : 0.0f;
    } else {
        int j = jbase + (t - BM); int jm = (j < SEQ) ? j : j - SEQ;
        mcol_s[t - BM] = mask[b * SEQ + jm] ? 1.0f : 0.0f;
    }

    // Staging: slot idx = w*64+lane holds row r0 = idx>>2, stored chunk idx&3,
    // i.e. LOGICAL chunk p0 = (idx&3) ^ swz(r0).  swz(r0+64) == swz(r0).
    int idx = w * 64 + lane;
    int r0 = idx >> 2;
    int p0 = (idx & 3) ^ swz(r0);
    const char* asrc0 = (const char*)(fb + (size_t)(ibase + r0) * DIM) + p0 * 16;
    const char* asrc1 = (const char*)(fb + (size_t)(ibase + r0 + 64) * DIM) + p0 * 16;
    const char* bsrc0 = (const char*)(fb + (size_t)(jbase + r0) * DIM) + p0 * 16;
    const char* bsrc1 = (const char*)(fb + (size_t)(jbase + r0 + 64) * DIM) + p0 * 16;

    auto stage = [&](int k0, int buf) {
        size_t kb = (size_t)k0 * 2;         // byte offset along k
        char* ab = (char*)&As[buf][0][0];
        char* bb = (char*)&Bs[buf][0][0];
        async_ld16(asrc0 + kb, ab + w * 1024);
        async_ld16(asrc1 + kb, ab + 4096 + w * 1024);
        async_ld16(bsrc0 + kb, bb + w * 1024);
        async_ld16(bsrc1 + kb, bb + 4096 + w * 1024);
    };

    f32x4 acc[4][4] = {};
    stage(0, 0);

    int buf = 0;
    #pragma unroll 1
    for (int it = 0; it < KITERS; it++) {
        __syncthreads();   // compiler emits vmcnt(0): drains exactly buf's DMAs
        if (it + 1 < KITERS) stage((it + 1) * BK, buf ^ 1);

        bf16x8 af[4], bfr[4];
        #pragma unroll
        for (int mi = 0; mi < 4; mi++) {
            int row = wrow * 64 + mi * 16 + colq;
            af[mi] = *(const bf16x8*)&As[buf][row][(quad ^ swz(row)) * 8];
        }
        #pragma unroll
        for (int nj = 0; nj < 4; nj++) {
            int row = wcol * 64 + nj * 16 + colq;
            bfr[nj] = *(const bf16x8*)&Bs[buf][row][(quad ^ swz(row)) * 8];
        }

        #pragma unroll
        for (int mi = 0; mi < 4; mi++)
            #pragma unroll
            for (int nj = 0; nj < 4; nj++)
                acc[mi][nj] = __builtin_amdgcn_mfma_f32_16x16x32_bf16(
                    af[mi], bfr[nj], acc[mi][nj], 0, 0, 0);
        buf ^= 1;
    }

    // Epilogue.  C/D layout: col = colq, row = quad*4 + reg.
    float mj[4]; int jglob[4];
    #pragma unroll
    for (int nj = 0; nj < 4; nj++) {
        int jl = wcol * 64 + nj * 16 + colq;
        mj[nj] = mcol_s[jl];
        jglob[nj] = jbase + jl;
    }
    float colsum[4] = {0.f, 0.f, 0.f, 0.f};

    #pragma unroll
    for (int mi = 0; mi < 4; mi++) {
        int il0 = wrow * 64 + mi * 16 + quad * 4;
        float rsum[4] = {0.f, 0.f, 0.f, 0.f};
        float mr[4];
        #pragma unroll
        for (int r = 0; r < 4; r++) mr[r] = mrow_s[il0 + r];
        #pragma unroll
        for (int nj = 0; nj < 4; nj++) {
            #pragma unroll
            for (int r = 0; r < 4; r++) {
                int d = (ibase + il0 + r) - jglob[nj];
                bool same = (d == 0) | (d == SEQ) | (d == -SEQ);
                float e = same ? 0.0f : __expf(acc[mi][nj][r] * TEMP_INV);
                rsum[r] += e * mj[nj];
                colsum[nj] += e * mr[r];
            }
        }
        // reduce each row sum across the 16 column lanes
        #pragma unroll
        for (int r = 0; r < 4; r++) {
            float v = rsum[r];
            #pragma unroll
            for (int m = 1; m < 16; m <<= 1) v += __shfl_xor(v, m, 64);
            if (colq == 0)
                atomicAdd(&Ng[b * SEQ2 + ibase + il0 + r], v);
        }
    }

    if (!isdiag) {
        // reduce col sums across the 4 quads
        #pragma unroll
        for (int nj = 0; nj < 4; nj++) {
            float v = colsum[nj];
            v += __shfl_xor(v, 16, 64);
            v += __shfl_xor(v, 32, 64);
            if (quad == 0)
                atomicAdd(&Ng[b * SEQ2 + jglob[nj]], v);
        }
    }
}

// ---------------------------------------------------------------------------
// Kernel 3: per-batch masked mean of per-token loss.
// per_tok[i] = log1p(Ng[i] * exp(-pos_sim/T))
// ---------------------------------------------------------------------------
__global__ __launch_bounds__(256) void loss_kernel(
        const float* __restrict__ Ng, const float* __restrict__ pos_cos,
        const int* __restrict__ mask, float* __restrict__ per_sample) {
    int b = blockIdx.x, t = threadIdx.x;
    float sum = 0.f, cnt = 0.f;
    for (int i = t; i < SEQ2; i += 256) {
        int im = (i < SEQ) ? i : i - SEQ;
        if (mask[b * SEQ + im]) {
            float ps = pos_cos[b * SEQ + im] * TEMP_INV;
            float ng = Ng[b * SEQ2 + i];
            sum += log1pf(ng * __expf(-ps));
            cnt += 1.0f;
        }
    }
    sum = wave_red64(sum); cnt = wave_red64(cnt);
    __shared__ float rs[4], rc[4];
    int lane = t & 63, w = t >> 6;
    if (lane == 0) { rs[w] = sum; rc[w] = cnt; }
    __syncthreads();
    if (t == 0) {
        float s = rs[0]+rs[1]+rs[2]+rs[3];
        float c = rc[0]+rc[1]+rc[2]+rc[3];
        per_sample[b] = s / c;
    }
}

__global__ void final_kernel(const float* __restrict__ per_sample, float* __restrict__ out) {
    if (threadIdx.x == 0) {
        float s = 0.f;
        #pragma unroll
        for (int b = 0; b < BATCH; b++) s += per_sample[b];
        out[0] = s / (float)BATCH;
    }
}

// ---------------------------------------------------------------------------
extern "C" void kernel_launch(void* const* d_in, const int* in_sizes, int n_in,
                              void* d_out, int out_size, void* d_ws, size_t ws_size,
                              hipStream_t stream) {
    const float* h1  = (const float*)d_in[0];
    const float* h2  = (const float*)d_in[1];
    const int* mask  = (const int*)d_in[2];
    float* out       = (float*)d_out;

    char* ws = (char*)d_ws;
    size_t feats_bytes = (size_t)BATCH * SEQ2 * DIM * 2;      // 50,331,648
    __hip_bfloat16* feats = (__hip_bfloat16*)ws;
    float* pos_cos    = (float*)(ws + feats_bytes);
    float* Ng         = (float*)(ws + feats_bytes + (size_t)BATCH * SEQ * 4);
    float* per_sample = (float*)(ws + feats_bytes + (size_t)BATCH * SEQ * 4
                                 + (size_t)BATCH * SEQ2 * 4);

    normalize_kernel<<<BATCH * SEQ / 4, 256, 0, stream>>>(h1, h2, feats, pos_cos, Ng);

    dim3 g2(NPAIRS, 1, BATCH);
    gemm_ng_kernel<<<g2, 256, 0, stream>>>(feats, mask, Ng);

    loss_kernel<<<BATCH, 256, 0, stream>>>(Ng, pos_cos, mask, per_sample);
    final_kernel<<<1, 64, 0, stream>>>(per_sample, out);
}